// Round 13
// baseline (144.871 us; speedup 1.0000x reference)
//
#include <hip/hip_runtime.h>
#include <hip/hip_bf16.h>

// B=4, C=256, N=HW=4096, Dqk=32.
// Round 21: R20 confirmed best config (133.0us; attn 51.8 = its 6-way-
// falsified floor). Last controllable lever: the wpack LAUNCH BOUNDARY.
// Fused-line data: REST(2 launches) ~63-65 vs REST(3) ~81us. Fix without any
// grid barrier: fold W-packing INTO qkv -- each wave owns m-tiles
// {2wid,2wid+1}, reads its own raw f32 W rows (L2-resident, 320KB total) and
// converts to f16 A-frags in registers per ks-step. wpack kernel DELETED ->
// 2 launches. Cost: W L2 traffic 82->164MB (~5us GPU-wide) + ~128 cvt/wave,
// absorbed by qkv's idle pipes. attn byte-identical to R20.
// Decisive: total ~120-128 => boundary cost real; ~131-135 => overhead is
// fixed harness restores => declare roofline next round.
// Carried: wave-specialized attn (8 PV + 8 S), K-dedup, conflict-free
// 16B-slot P layout, x2 unroll named reg sets, SGPR-base addressing, &63
// wrap prefetch, packed-Vp, S^T trick, LDS-only barrier, XCD swizzle,
// no-max softmax, LOG2E folded into W_q/b_q.

#define N_PIX 4096
#define DQK   32
#define CCH   256
#define LOG2E 1.44269504088896f

typedef __attribute__((ext_vector_type(8))) _Float16 f16x8;
typedef __attribute__((ext_vector_type(4))) _Float16 f16x4;
typedef __attribute__((ext_vector_type(2))) _Float16 f16x2;
typedef __attribute__((ext_vector_type(8))) short    bf16x8;
typedef __attribute__((ext_vector_type(4))) short    bf16x4;
typedef __attribute__((ext_vector_type(4))) float    f32x4;

// LDS-only block barrier: waits lgkmcnt(0) but leaves vmcnt untouched.
__device__ inline void barrier_lds() {
    asm volatile("" ::: "memory");
    __builtin_amdgcn_s_waitcnt(0xc07f);   // vmcnt=63, expcnt=7, lgkmcnt=0
    __builtin_amdgcn_s_barrier();
    asm volatile("" ::: "memory");
}

// pack two f32 -> two bf16 in one instruction (RNE)
__device__ inline unsigned cvt_pk_bf16(float lo, float hi) {
    unsigned r;
    asm("v_cvt_pk_bf16_f32 %0, %1, %2" : "=v"(r) : "v"(lo), "v"(hi));
    return r;
}

// ---------------------------------------------------------------------------
// Kernel 1: QKV projection with IN-KERNEL W packing (wpack launch removed).
// Grid 512, 640 thr = 10 waves, 32-pixel tiles. Wave wid owns m-tiles
// {2*wid, 2*wid+1}; per ks-step it loads its two A-frags DIRECTLY from raw
// f32 W (rows m0+L15, cols ks*32+quad*8..+8; LOG2E folded into Wq) and
// converts to f16 in registers; frags reused across both 16-pixel halves.
// V output goes through LDS transpose -> packed B-frag layout:
//   Vp[b][(n0>>5)*16 + cg16][lane(quad,L15)][j] = v[cg16*16+L15][n0 + quad*8+j]
// ---------------------------------------------------------------------------
__global__ __launch_bounds__(640, 5) void qkv_kernel(
    const float* __restrict__ x,
    const float* __restrict__ Wq, const float* __restrict__ Wk,
    const float* __restrict__ Wv,
    const float* __restrict__ bq, const float* __restrict__ bk,
    const float* __restrict__ bv,
    _Float16* __restrict__ qo, _Float16* __restrict__ ko,
    __hip_bfloat16* __restrict__ vp)
{
    // shared: xT (32x264 f16 = 16.9KB) then reused as vst (256x40 bf16 = 20KB)
    __shared__ alignas(16) unsigned char shraw[256 * 40 * 2];
    _Float16       (*xT)[264] = (_Float16 (*)[264])shraw;
    __hip_bfloat16 (*vst)[40] = (__hip_bfloat16 (*)[40])shraw;

    const int idx = blockIdx.x;
    const int b   = (idx & 7) >> 1;
    const int n0  = (((idx >> 3) << 1) | (idx & 1)) * 32;
    const int tid = threadIdx.x;

    // stage x[256c][32n] -> xT[n][c] f16  (1024 slots over 640 threads)
    {
        const float* xb = x + (size_t)b * CCH * N_PIX;
        #pragma unroll
        for (int pass = 0; pass < 2; ++pass) {
            const int slot = pass * 640 + tid;
            if (slot < 1024) {
                const int c2 = (slot >> 3) * 2;
                const int n4 = (slot & 7) * 4;
                const float4 r0 = *(const float4*)(xb + (size_t)c2       * N_PIX + n0 + n4);
                const float4 r1 = *(const float4*)(xb + (size_t)(c2 + 1) * N_PIX + n0 + n4);
                const float a[4] = {r0.x, r0.y, r0.z, r0.w};
                const float c[4] = {r1.x, r1.y, r1.z, r1.w};
                #pragma unroll
                for (int i = 0; i < 4; ++i)
                    *(f16x2*)(&xT[n4 + i][c2]) = (f16x2){(_Float16)a[i], (_Float16)c[i]};
            }
        }
    }
    __syncthreads();

    const int lane = tid & 63;
    const int wid  = tid >> 6;   // 0..9, owns m-tiles {2wid, 2wid+1}
    const int L15  = lane & 15;
    const int quad = lane >> 4;

    const f32x4 fz = {0.f, 0.f, 0.f, 0.f};
    f32x4 acc[2][2];   // [j (m-tile)][nf (pixel half)]
    #pragma unroll
    for (int j = 0; j < 2; ++j) { acc[j][0] = fz; acc[j][1] = fz; }

    // per-wave raw-W row pointers + scales (replaces packed Wp)
    const float* wsrc[2];
    float wsc[2];
    #pragma unroll
    for (int j = 0; j < 2; ++j) {
        const int m0 = (wid * 2 + j) * 16;
        if (m0 < 32)      { wsrc[j] = Wq + (size_t)(m0      + L15) * 256; wsc[j] = LOG2E; }
        else if (m0 < 64) { wsrc[j] = Wk + (size_t)(m0 - 32 + L15) * 256; wsc[j] = 1.f; }
        else              { wsrc[j] = Wv + (size_t)(m0 - 64 + L15) * 256; wsc[j] = 1.f; }
    }

    #pragma unroll
    for (int ks = 0; ks < 8; ++ks) {
        f16x8 afr[2];
        #pragma unroll
        for (int j = 0; j < 2; ++j) {
            const float* p = wsrc[j] + ks * 32 + quad * 8;
            const float4 lo = *(const float4*)p;
            const float4 hi = *(const float4*)(p + 4);
            afr[j][0] = (_Float16)(lo.x * wsc[j]);
            afr[j][1] = (_Float16)(lo.y * wsc[j]);
            afr[j][2] = (_Float16)(lo.z * wsc[j]);
            afr[j][3] = (_Float16)(lo.w * wsc[j]);
            afr[j][4] = (_Float16)(hi.x * wsc[j]);
            afr[j][5] = (_Float16)(hi.y * wsc[j]);
            afr[j][6] = (_Float16)(hi.z * wsc[j]);
            afr[j][7] = (_Float16)(hi.w * wsc[j]);
        }
        #pragma unroll
        for (int nf = 0; nf < 2; ++nf) {
            const f16x8 bfr = *(const f16x8*)(&xT[nf * 16 + L15][ks * 32 + quad * 8]);
            acc[0][nf] = __builtin_amdgcn_mfma_f32_16x16x32_f16(afr[0], bfr, acc[0][nf], 0, 0, 0);
            acc[1][nf] = __builtin_amdgcn_mfma_f32_16x16x32_f16(afr[1], bfr, acc[1][nf], 0, 0, 0);
        }
    }

    // q/k epilogue (global, no LDS): C/D row = out-row (quad*4+r), col = pixel (L15)
    #pragma unroll
    for (int j = 0; j < 2; ++j) {
        const int m0 = (wid * 2 + j) * 16;
        if (m0 < 32) {
            const int mr = m0 + quad * 4;
            #pragma unroll
            for (int nf = 0; nf < 2; ++nf) {
                const int n = n0 + nf * 16 + L15;
                f16x4 h;
                #pragma unroll
                for (int r = 0; r < 4; ++r) h[r] = (_Float16)(acc[j][nf][r] + bq[mr + r] * LOG2E);
                *(f16x4*)(qo + ((size_t)b * N_PIX + n) * DQK + mr) = h;
            }
        } else if (m0 < 64) {
            const int mr = m0 - 32 + quad * 4;
            #pragma unroll
            for (int nf = 0; nf < 2; ++nf) {
                const int n = n0 + nf * 16 + L15;
                f16x4 h;
                #pragma unroll
                for (int r = 0; r < 4; ++r) h[r] = (_Float16)(acc[j][nf][r] + bk[mr + r]);
                *(f16x4*)(ko + ((size_t)b * N_PIX + n) * DQK + mr) = h;
            }
        }
    }

    __syncthreads();   // xT dead; vst aliases it

    // v -> LDS transpose buffer vst[ch][pix] (rows padded to 40 elems, 16B-aligned)
    #pragma unroll
    for (int j = 0; j < 2; ++j) {
        const int m0 = (wid * 2 + j) * 16;
        if (m0 >= 64) {
            const int c = m0 - 64 + quad * 4;
            #pragma unroll
            for (int nf = 0; nf < 2; ++nf) {
                const int np = nf * 16 + L15;
                #pragma unroll
                for (int r = 0; r < 4; ++r)
                    vst[c + r][np] = __float2bfloat16(acc[j][nf][r] + bv[c + r]);
            }
        }
    }
    __syncthreads();

    // packed store: slot (cg16, lane'=(qd,l15)) -> one b128 LDS read + one 16B store
    {
        __hip_bfloat16* vpb = vp + (size_t)b * 2048 * 512 + (size_t)((n0 >> 5) * 16) * 512;
        #pragma unroll
        for (int s = 0; s < 2; ++s) {
            const int slot = s * 640 + tid;   // 0..1279, use 0..1023
            if (slot < 1024) {
                const int cg16 = slot >> 6;
                const int ln   = slot & 63;
                const int qd   = ln >> 4;
                const int l15  = ln & 15;
                const bf16x8 val = *(const bf16x8*)(&vst[cg16 * 16 + l15][qd * 8]);
                *(bf16x8*)(vpb + ((size_t)cg16 * 64 + ln) * 8) = val;
            }
        }
    }
}

// ---------------------------------------------------------------------------
// Kernel 2: attention (exact R15/R20 config -- best measured, 51.8us).
// Grid 256 (XCD-swizzled), 1024 threads = 16 waves, 64 q/block, 1 block/CU.
// Wave-specialized, 2-buffer P, barrier per body.
//   PV waves (wid 0..7): cg owns 32 ch x all 64 q (byte-optimal blocking).
//   S waves (wid 8..15): (skt = wid&3, h = (wid>>2)&1): k-tile skt for
//     q-tiles {2h, 2h+1}. ONE 1KB K-frag per body feeds 2 MFMAs (K-dedup).
// P layout: Ps[buf][g][kb8][L15][8e]; tile (sqt,kt) -> group g = sqt*2+(kt>>1),
// slot kb8 = (kt&1)*2+(quad>>1), elem (quad&1)*4. PV reads 1KB contiguous
// (0 conflicts), S uint2 writes 4/bank balanced.
// ---------------------------------------------------------------------------

#define PV_BODY(J, VR)                                                            \
  {                                                                               \
    const int buf_ = (J) & 1;                                                     \
    _Pragma("unroll")                                                             \
    for (int qq_ = 0; qq_ < 4; ++qq_) {                                           \
      _Pragma("unroll")                                                           \
      for (int kk_ = 0; kk_ < 2; ++kk_) {                                         \
        const bf16x8 ap_ = *(const bf16x8*)(&Ps[buf_][qq_ * 2 + kk_][quad][L15][0]); \
        oacc[qq_][0] = __builtin_amdgcn_mfma_f32_16x16x32_bf16(                   \
            ap_, VR[kk_][0], oacc[qq_][0], 0, 0, 0);                              \
        oacc[qq_][1] = __builtin_amdgcn_mfma_f32_16x16x32_bf16(                   \
            ap_, VR[kk_][1], oacc[qq_][1], 0, 0, 0);                              \
      }                                                                           \
    }                                                                             \
    const __hip_bfloat16* vt_ = vb + (size_t)(((J) + 2) & 63) * 16384;            \
    _Pragma("unroll")                                                             \
    for (int kk_ = 0; kk_ < 2; ++kk_)                                             \
      _Pragma("unroll")                                                           \
      for (int cf_ = 0; cf_ < 2; ++cf_)                                           \
        VR[kk_][cf_] = *(const bf16x8*)(vt_ + voff0 + kk_ * 8192 + cf_ * 512);    \
  }

// S body J: computes S(J+1) for tiles (2h,skt),(2h+1,skt) from KR = K(J+1),
// writes P(J+1) to buf (J&1)^1, prefetches K(J+3) into KR.
#define S_BODY(J, KR, DO_S)                                                       \
  {                                                                               \
    if (DO_S) {                                                                   \
      const int bufw_ = ((J) & 1) ^ 1;                                            \
      const f32x4 s0_ = __builtin_amdgcn_mfma_f32_16x16x32_f16(KR, aq0, fz, 0, 0, 0); \
      const f32x4 s1_ = __builtin_amdgcn_mfma_f32_16x16x32_f16(KR, aq1, fz, 0, 0, 0); \
      const _Float16* kp_ = kbp + (size_t)(((J) + 3) & 63) * (64 * DQK);          \
      KR = *(const f16x8*)(kp_ + koff);                                           \
      const float a0_ = exp2f(s0_[0]), a1_ = exp2f(s0_[1]);                       \
      const float a2_ = exp2f(s0_[2]), a3_ = exp2f(s0_[3]);                       \
      psum0 += (a0_ + a1_) + (a2_ + a3_);                                         \
      uint2 w0_; w0_.x = cvt_pk_bf16(a0_, a1_); w0_.y = cvt_pk_bf16(a2_, a3_);    \
      *(uint2*)(&Ps[bufw_][g0][s8][L15][e4]) = w0_;                               \
      const float b0_ = exp2f(s1_[0]), b1_ = exp2f(s1_[1]);                       \
      const float b2_ = exp2f(s1_[2]), b3_ = exp2f(s1_[3]);                       \
      psum1 += (b0_ + b1_) + (b2_ + b3_);                                         \
      uint2 w1_; w1_.x = cvt_pk_bf16(b0_, b1_); w1_.y = cvt_pk_bf16(b2_, b3_);    \
      *(uint2*)(&Ps[bufw_][g1][s8][L15][e4]) = w1_;                               \
    }                                                                             \
  }

__global__ __launch_bounds__(1024, 4) void attn_kernel(
    const _Float16* __restrict__ qg,        // [B][N][32], q pre-scaled by log2e
    const _Float16* __restrict__ kg,        // [B][N][32]
    const __hip_bfloat16* __restrict__ vp,  // packed: [B][2048 chunks][64][8]
    float* __restrict__ out)                // [B][C][N]
{
    __shared__ __hip_bfloat16 Ps[2][8][4][16][8];   // 16KB; [buf][g][kb8][L15][e]
    __shared__ float lsum[4][4][16];                // [sqt][kt][query]

    const int idx  = blockIdx.x;
    const int b    = (idx & 7) >> 1;
    const int n0   = (((idx >> 3) << 1) | (idx & 1)) * 64;
    const int tid  = threadIdx.x;
    const int wid  = tid >> 6;
    const int lane = tid & 63;
    const int L15  = lane & 15;
    const int quad = lane >> 4;
    const bool is_pv = (wid < 8);

    const f32x4 fz = {0.f, 0.f, 0.f, 0.f};

    // ---- PV-wave state (wid 0..7)
    const int cg = wid & 7;                        // 32-channel group
    const __hip_bfloat16* vb = vp + (size_t)b * 2048 * 512;
    const int voff0 = lane * 8 + cg * 2 * 512;     // + kk*8192 + cf*512
    f32x4 oacc[4][2];
    #pragma unroll
    for (int qq = 0; qq < 4; ++qq) { oacc[qq][0] = fz; oacc[qq][1] = fz; }
    bf16x8 vA[2][2], vB[2][2];

    // ---- S-wave state (wid 8..15): skt = wid&3 (k-tile), h = (wid>>2)&1
    //      tiles (sqt=2h, skt) and (sqt=2h+1, skt); ONE K-frag per body.
    const int skt = wid & 3;
    const int h   = (wid >> 2) & 1;
    const int g0  = 4 * h + (skt >> 1);            // group of tile (2h, skt)
    const int g1  = g0 + 2;                        // group of tile (2h+1, skt)
    const int s8  = (skt & 1) * 2 + (quad >> 1);   // kb8 slot within group
    const int e4  = (quad & 1) * 4;                // element offset
    const _Float16* kbp = kg + (size_t)b * N_PIX * DQK;
    const int koff = (skt * 16 + L15) * DQK + quad * 8;
    f16x8 aq0{}, aq1{}, kA{}, kB{};
    float psum0 = 0.f, psum1 = 0.f;

    // ---- prologue
    if (is_pv) {
        #pragma unroll
        for (int kk = 0; kk < 2; ++kk)
            #pragma unroll
            for (int cf = 0; cf < 2; ++cf) {
                vA[kk][cf] = *(const bf16x8*)(vb +                 voff0 + kk * 8192 + cf * 512);
                vB[kk][cf] = *(const bf16x8*)(vb + (size_t)16384 + voff0 + kk * 8192 + cf * 512);
            }
    } else {
        aq0 = *(const f16x8*)(qg + ((size_t)b * N_PIX + n0 + (2 * h + 0) * 16 + L15) * DQK + quad * 8);
        aq1 = *(const f16x8*)(qg + ((size_t)b * N_PIX + n0 + (2 * h + 1) * 16 + L15) * DQK + quad * 8);
        const f16x8 k00 = *(const f16x8*)(kbp + koff);
        kA = *(const f16x8*)(kbp + (size_t)1 * 64 * DQK + koff);
        kB = *(const f16x8*)(kbp + (size_t)2 * 64 * DQK + koff);
        const f32x4 s0 = __builtin_amdgcn_mfma_f32_16x16x32_f16(k00, aq0, fz, 0, 0, 0);
        const f32x4 s1 = __builtin_amdgcn_mfma_f32_16x16x32_f16(k00, aq1, fz, 0, 0, 0);
        const float a0 = exp2f(s0[0]), a1 = exp2f(s0[1]);
        const float a2 = exp2f(s0[2]), a3 = exp2f(s0[3]);
        psum0 += (a0 + a1) + (a2 + a3);
        uint2 w0; w0.x = cvt_pk_bf16(a0, a1); w0.y = cvt_pk_bf16(a2, a3);
        *(uint2*)(&Ps[0][g0][s8][L15][e4]) = w0;
        const float b0 = exp2f(s1[0]), b1 = exp2f(s1[1]);
        const float b2 = exp2f(s1[2]), b3 = exp2f(s1[3]);
        psum1 += (b0 + b1) + (b2 + b3);
        uint2 w1; w1.x = cvt_pk_bf16(b0, b1); w1.y = cvt_pk_bf16(b2, b3);
        *(uint2*)(&Ps[0][g1][s8][L15][e4]) = w1;
    }
    barrier_lds();

    // ---- main loop: 64 bodies, x2 unrolled (P(J) lives in buf J&1)
    for (int it = 0; it < 64; it += 2) {
        if (is_pv) { PV_BODY(it, vA) } else { S_BODY(it, kA, true) }
        barrier_lds();
        if (is_pv) { PV_BODY(it + 1, vB) } else { S_BODY(it + 1, kB, it < 62) }
        barrier_lds();
    }

    // ---- epilogue: S waves publish row-sums, PV waves normalize + store
    if (!is_pv) {
        psum0 += __shfl_xor(psum0, 16, 64);
        psum0 += __shfl_xor(psum0, 32, 64);
        psum1 += __shfl_xor(psum1, 16, 64);
        psum1 += __shfl_xor(psum1, 32, 64);
        if (quad == 0) {
            lsum[2 * h + 0][skt][L15] = psum0;
            lsum[2 * h + 1][skt][L15] = psum1;
        }
    }
    __syncthreads();

    if (is_pv) {
        float* ob = out + (size_t)b * CCH * N_PIX;
        #pragma unroll
        for (int qq = 0; qq < 4; ++qq) {
            float inv_l[4];
            #pragma unroll
            for (int r = 0; r < 4; ++r) {
                const int q = quad * 4 + r;
                inv_l[r] = 1.f / (lsum[qq][0][q] + lsum[qq][1][q] +
                                  lsum[qq][2][q] + lsum[qq][3][q]);
            }
            #pragma unroll
            for (int cf = 0; cf < 2; ++cf) {
                const int c = cg * 32 + cf * 16 + L15;
                f32x4 o;
                #pragma unroll
                for (int r = 0; r < 4; ++r) o[r] = oacc[qq][cf][r] * inv_l[r];
                *(f32x4*)(ob + (size_t)c * N_PIX + n0 + qq * 16 + quad * 4) = o;
            }
        }
    }
}

// ---------------------------------------------------------------------------
extern "C" void kernel_launch(void* const* d_in, const int* in_sizes, int n_in,
                              void* d_out, int out_size, void* d_ws, size_t ws_size,
                              hipStream_t stream) {
    (void)in_sizes; (void)n_in; (void)out_size; (void)ws_size;
    const float* x  = (const float*)d_in[0];
    const float* Wq = (const float*)d_in[1];
    const float* bq = (const float*)d_in[2];
    const float* Wk = (const float*)d_in[3];
    const float* bk = (const float*)d_in[4];
    const float* Wv = (const float*)d_in[5];
    const float* bv = (const float*)d_in[6];

    // workspace: q 1MB | k 1MB | Vp 8MB
    _Float16* qb = (_Float16*)d_ws;
    _Float16* kb = qb + (size_t)4 * N_PIX * DQK;
    __hip_bfloat16* vpk = (__hip_bfloat16*)(kb + (size_t)4 * N_PIX * DQK);
    float* outp = (float*)d_out;

    qkv_kernel<<<512, 640, 0, stream>>>(x, Wq, Wk, Wv, bq, bk, bv, qb, kb, vpk);
    attn_kernel<<<256, 1024, 0, stream>>>(qb, kb, vpk, outp);
}

// Round 14
// 134.381 us; speedup vs baseline: 1.0781x; 1.0781x over previous
//
#include <hip/hip_runtime.h>
#include <hip/hip_bf16.h>

// B=4, C=256, N=HW=4096, Dqk=32.
// Round 22: FINAL — revert to R20 (best measured: 133.0us; attn 51.8us).
// R21 falsified the launch-boundary lever: folding W-pack into qkv cost +12us
// (scattered 16-row W reads on the MFMA critical path x512 blocks > boundary
// saving). Session ledger: attn pinned at ~1960 cyc/body across SIX falsified
// structural theories (VALU R9, barrier domains R10, vector BW R11, pipeline
// depth R13, byte totals -32% R16, wave count R16); qkv insensitive across 3
// implementations; fusion pathological (R17-R19, 3.8x stretch, mechanism
// unidentified); REST ~56us is harness restore-dispatches + launch gaps.
// Empirical floor for this decomposition: ~133us total.
// Carried: wave-specialized attn (8 PV + 8 S waves), K-dedup (one K-frag
// feeds 2 q-tile MFMAs), conflict-free 16B-slot P layout, x2 unroll named
// reg sets, SGPR-base addressing, &63 wrap prefetch, packed-Vp, S^T trick,
// LDS-only barrier, XCD swizzle, packed-W qkv (640-thr, W-dedup), no-max SM.

#define N_PIX 4096
#define DQK   32
#define CCH   256
#define LOG2E 1.44269504088896f

typedef __attribute__((ext_vector_type(8))) _Float16 f16x8;
typedef __attribute__((ext_vector_type(4))) _Float16 f16x4;
typedef __attribute__((ext_vector_type(2))) _Float16 f16x2;
typedef __attribute__((ext_vector_type(8))) short    bf16x8;
typedef __attribute__((ext_vector_type(4))) short    bf16x4;
typedef __attribute__((ext_vector_type(4))) float    f32x4;

// LDS-only block barrier: waits lgkmcnt(0) but leaves vmcnt untouched.
__device__ inline void barrier_lds() {
    asm volatile("" ::: "memory");
    __builtin_amdgcn_s_waitcnt(0xc07f);   // vmcnt=63, expcnt=7, lgkmcnt=0
    __builtin_amdgcn_s_barrier();
    asm volatile("" ::: "memory");
}

// pack two f32 -> two bf16 in one instruction (RNE)
__device__ inline unsigned cvt_pk_bf16(float lo, float hi) {
    unsigned r;
    asm("v_cvt_pk_bf16_f32 %0, %1, %2" : "=v"(r) : "v"(lo), "v"(hi));
    return r;
}

// ---------------------------------------------------------------------------
// Kernel 0: pack Wq|Wk|Wv -> f16 A-fragments, lane-ordered (LOG2E folded into Wq).
// ---------------------------------------------------------------------------
__global__ __launch_bounds__(256) void wpack_kernel(
    const float* __restrict__ Wq, const float* __restrict__ Wk,
    const float* __restrict__ Wv, _Float16* __restrict__ Wp)
{
    const int tid   = threadIdx.x;
    const int wflat = blockIdx.x * 4 + (tid >> 6);   // 0..159
    const int lane  = tid & 63;
    const int L15   = lane & 15;
    const int quad  = lane >> 4;
    const int mt    = wflat >> 3;
    const int ks    = wflat & 7;
    const int m0    = mt * 16;

    const float* Wsrc; int row; float scale = 1.f;
    if (m0 < 32)      { Wsrc = Wq; row = m0 + L15;      scale = LOG2E; }
    else if (m0 < 64) { Wsrc = Wk; row = m0 - 32 + L15; }
    else              { Wsrc = Wv; row = m0 - 64 + L15; }

    const float* p = Wsrc + (size_t)row * 256 + ks * 32 + quad * 8;
    f16x8 h;
    #pragma unroll
    for (int j = 0; j < 8; ++j) h[j] = (_Float16)(p[j] * scale);
    *(f16x8*)(Wp + ((size_t)wflat * 64 + lane) * 8) = h;
}

// ---------------------------------------------------------------------------
// Kernel 1: QKV projection, f16 MFMA, packed W. Grid 512, 640 thr = 10 waves,
// 32-pixel tiles. Wave wid owns m-tiles {2*wid, 2*wid+1}; A-frags held in
// registers per ks-step and reused across BOTH 16-pixel halves.
// V output goes through LDS transpose -> packed B-frag layout:
//   Vp[b][(n0>>5)*16 + cg16][lane(quad,L15)][j] = v[cg16*16+L15][n0 + quad*8+j]
// ---------------------------------------------------------------------------
__global__ __launch_bounds__(640, 5) void qkv_kernel(
    const float* __restrict__ x, const _Float16* __restrict__ Wp,
    const float* __restrict__ bq, const float* __restrict__ bk,
    const float* __restrict__ bv,
    _Float16* __restrict__ qo, _Float16* __restrict__ ko,
    __hip_bfloat16* __restrict__ vp)
{
    // shared: xT (32x264 f16 = 16.9KB) then reused as vst (256x40 bf16 = 20KB)
    __shared__ alignas(16) unsigned char shraw[256 * 40 * 2];
    _Float16       (*xT)[264] = (_Float16 (*)[264])shraw;
    __hip_bfloat16 (*vst)[40] = (__hip_bfloat16 (*)[40])shraw;

    const int idx = blockIdx.x;
    const int b   = (idx & 7) >> 1;
    const int n0  = (((idx >> 3) << 1) | (idx & 1)) * 32;
    const int tid = threadIdx.x;

    // stage x[256c][32n] -> xT[n][c] f16  (1024 slots over 640 threads)
    {
        const float* xb = x + (size_t)b * CCH * N_PIX;
        #pragma unroll
        for (int pass = 0; pass < 2; ++pass) {
            const int slot = pass * 640 + tid;
            if (slot < 1024) {
                const int c2 = (slot >> 3) * 2;
                const int n4 = (slot & 7) * 4;
                const float4 r0 = *(const float4*)(xb + (size_t)c2       * N_PIX + n0 + n4);
                const float4 r1 = *(const float4*)(xb + (size_t)(c2 + 1) * N_PIX + n0 + n4);
                const float a[4] = {r0.x, r0.y, r0.z, r0.w};
                const float c[4] = {r1.x, r1.y, r1.z, r1.w};
                #pragma unroll
                for (int i = 0; i < 4; ++i)
                    *(f16x2*)(&xT[n4 + i][c2]) = (f16x2){(_Float16)a[i], (_Float16)c[i]};
            }
        }
    }
    __syncthreads();

    const int lane = tid & 63;
    const int wid  = tid >> 6;   // 0..9, owns m-tiles {2wid, 2wid+1}
    const int L15  = lane & 15;
    const int quad = lane >> 4;

    const f32x4 fz = {0.f, 0.f, 0.f, 0.f};
    f32x4 acc[2][2];   // [j (m-tile)][nf (pixel half)]
    #pragma unroll
    for (int j = 0; j < 2; ++j) { acc[j][0] = fz; acc[j][1] = fz; }

    const _Float16* wpw = Wp + ((size_t)(wid * 2) * 8 * 64 + lane) * 8;

    #pragma unroll
    for (int ks = 0; ks < 8; ++ks) {
        const f16x8 a0 = *(const f16x8*)(wpw + (size_t)(0 * 8 + ks) * 512);
        const f16x8 a1 = *(const f16x8*)(wpw + (size_t)(1 * 8 + ks) * 512);
        #pragma unroll
        for (int nf = 0; nf < 2; ++nf) {
            const f16x8 bfr = *(const f16x8*)(&xT[nf * 16 + L15][ks * 32 + quad * 8]);
            acc[0][nf] = __builtin_amdgcn_mfma_f32_16x16x32_f16(a0, bfr, acc[0][nf], 0, 0, 0);
            acc[1][nf] = __builtin_amdgcn_mfma_f32_16x16x32_f16(a1, bfr, acc[1][nf], 0, 0, 0);
        }
    }

    // q/k epilogue (global, no LDS): C/D row = out-row (quad*4+r), col = pixel (L15)
    #pragma unroll
    for (int j = 0; j < 2; ++j) {
        const int m0 = (wid * 2 + j) * 16;
        if (m0 < 32) {
            const int mr = m0 + quad * 4;
            #pragma unroll
            for (int nf = 0; nf < 2; ++nf) {
                const int n = n0 + nf * 16 + L15;
                f16x4 h;
                #pragma unroll
                for (int r = 0; r < 4; ++r) h[r] = (_Float16)(acc[j][nf][r] + bq[mr + r] * LOG2E);
                *(f16x4*)(qo + ((size_t)b * N_PIX + n) * DQK + mr) = h;
            }
        } else if (m0 < 64) {
            const int mr = m0 - 32 + quad * 4;
            #pragma unroll
            for (int nf = 0; nf < 2; ++nf) {
                const int n = n0 + nf * 16 + L15;
                f16x4 h;
                #pragma unroll
                for (int r = 0; r < 4; ++r) h[r] = (_Float16)(acc[j][nf][r] + bk[mr + r]);
                *(f16x4*)(ko + ((size_t)b * N_PIX + n) * DQK + mr) = h;
            }
        }
    }

    __syncthreads();   // xT dead; vst aliases it

    // v -> LDS transpose buffer vst[ch][pix] (rows padded to 40 elems, 16B-aligned)
    #pragma unroll
    for (int j = 0; j < 2; ++j) {
        const int m0 = (wid * 2 + j) * 16;
        if (m0 >= 64) {
            const int c = m0 - 64 + quad * 4;
            #pragma unroll
            for (int nf = 0; nf < 2; ++nf) {
                const int np = nf * 16 + L15;
                #pragma unroll
                for (int r = 0; r < 4; ++r)
                    vst[c + r][np] = __float2bfloat16(acc[j][nf][r] + bv[c + r]);
            }
        }
    }
    __syncthreads();

    // packed store: slot (cg16, lane'=(qd,l15)) -> one b128 LDS read + one 16B store
    {
        __hip_bfloat16* vpb = vp + (size_t)b * 2048 * 512 + (size_t)((n0 >> 5) * 16) * 512;
        #pragma unroll
        for (int s = 0; s < 2; ++s) {
            const int slot = s * 640 + tid;   // 0..1279, use 0..1023
            if (slot < 1024) {
                const int cg16 = slot >> 6;
                const int ln   = slot & 63;
                const int qd   = ln >> 4;
                const int l15  = ln & 15;
                const bf16x8 val = *(const bf16x8*)(&vst[cg16 * 16 + l15][qd * 8]);
                *(bf16x8*)(vpb + ((size_t)cg16 * 64 + ln) * 8) = val;
            }
        }
    }
}

// ---------------------------------------------------------------------------
// Kernel 2: attention. Grid 256 (XCD-swizzled), 1024 threads = 16 waves,
// 64 q/block, 1 block/CU. Wave-specialized, 2-buffer P, barrier per body.
//   PV waves (wid 0..7): cg owns 32 ch x all 64 q (byte-optimal blocking).
//   S waves (wid 8..15): (skt = wid&3, h = (wid>>2)&1): k-tile skt for
//     q-tiles {2h, 2h+1}. ONE 1KB K-frag per body feeds 2 MFMAs (K-dedup).
// P layout: Ps[buf][g][kb8][L15][8e]; tile (sqt,kt) -> group g = sqt*2+(kt>>1),
// slot kb8 = (kt&1)*2+(quad>>1), elem (quad&1)*4. PV reads 1KB contiguous
// (0 conflicts), S uint2 writes 4/bank balanced.
// ---------------------------------------------------------------------------

#define PV_BODY(J, VR)                                                            \
  {                                                                               \
    const int buf_ = (J) & 1;                                                     \
    _Pragma("unroll")                                                             \
    for (int qq_ = 0; qq_ < 4; ++qq_) {                                           \
      _Pragma("unroll")                                                           \
      for (int kk_ = 0; kk_ < 2; ++kk_) {                                         \
        const bf16x8 ap_ = *(const bf16x8*)(&Ps[buf_][qq_ * 2 + kk_][quad][L15][0]); \
        oacc[qq_][0] = __builtin_amdgcn_mfma_f32_16x16x32_bf16(                   \
            ap_, VR[kk_][0], oacc[qq_][0], 0, 0, 0);                              \
        oacc[qq_][1] = __builtin_amdgcn_mfma_f32_16x16x32_bf16(                   \
            ap_, VR[kk_][1], oacc[qq_][1], 0, 0, 0);                              \
      }                                                                           \
    }                                                                             \
    const __hip_bfloat16* vt_ = vb + (size_t)(((J) + 2) & 63) * 16384;            \
    _Pragma("unroll")                                                             \
    for (int kk_ = 0; kk_ < 2; ++kk_)                                             \
      _Pragma("unroll")                                                           \
      for (int cf_ = 0; cf_ < 2; ++cf_)                                           \
        VR[kk_][cf_] = *(const bf16x8*)(vt_ + voff0 + kk_ * 8192 + cf_ * 512);    \
  }

// S body J: computes S(J+1) for tiles (2h,skt),(2h+1,skt) from KR = K(J+1),
// writes P(J+1) to buf (J&1)^1, prefetches K(J+3) into KR.
#define S_BODY(J, KR, DO_S)                                                       \
  {                                                                               \
    if (DO_S) {                                                                   \
      const int bufw_ = ((J) & 1) ^ 1;                                            \
      const f32x4 s0_ = __builtin_amdgcn_mfma_f32_16x16x32_f16(KR, aq0, fz, 0, 0, 0); \
      const f32x4 s1_ = __builtin_amdgcn_mfma_f32_16x16x32_f16(KR, aq1, fz, 0, 0, 0); \
      const _Float16* kp_ = kbp + (size_t)(((J) + 3) & 63) * (64 * DQK);          \
      KR = *(const f16x8*)(kp_ + koff);                                           \
      const float a0_ = exp2f(s0_[0]), a1_ = exp2f(s0_[1]);                       \
      const float a2_ = exp2f(s0_[2]), a3_ = exp2f(s0_[3]);                       \
      psum0 += (a0_ + a1_) + (a2_ + a3_);                                         \
      uint2 w0_; w0_.x = cvt_pk_bf16(a0_, a1_); w0_.y = cvt_pk_bf16(a2_, a3_);    \
      *(uint2*)(&Ps[bufw_][g0][s8][L15][e4]) = w0_;                               \
      const float b0_ = exp2f(s1_[0]), b1_ = exp2f(s1_[1]);                       \
      const float b2_ = exp2f(s1_[2]), b3_ = exp2f(s1_[3]);                       \
      psum1 += (b0_ + b1_) + (b2_ + b3_);                                         \
      uint2 w1_; w1_.x = cvt_pk_bf16(b0_, b1_); w1_.y = cvt_pk_bf16(b2_, b3_);    \
      *(uint2*)(&Ps[bufw_][g1][s8][L15][e4]) = w1_;                               \
    }                                                                             \
  }

__global__ __launch_bounds__(1024, 4) void attn_kernel(
    const _Float16* __restrict__ qg,        // [B][N][32], q pre-scaled by log2e
    const _Float16* __restrict__ kg,        // [B][N][32]
    const __hip_bfloat16* __restrict__ vp,  // packed: [B][2048 chunks][64][8]
    float* __restrict__ out)                // [B][C][N]
{
    __shared__ __hip_bfloat16 Ps[2][8][4][16][8];   // 16KB; [buf][g][kb8][L15][e]
    __shared__ float lsum[4][4][16];                // [sqt][kt][query]

    const int idx  = blockIdx.x;
    const int b    = (idx & 7) >> 1;
    const int n0   = (((idx >> 3) << 1) | (idx & 1)) * 64;
    const int tid  = threadIdx.x;
    const int wid  = tid >> 6;
    const int lane = tid & 63;
    const int L15  = lane & 15;
    const int quad = lane >> 4;
    const bool is_pv = (wid < 8);

    const f32x4 fz = {0.f, 0.f, 0.f, 0.f};

    // ---- PV-wave state (wid 0..7)
    const int cg = wid & 7;                        // 32-channel group
    const __hip_bfloat16* vb = vp + (size_t)b * 2048 * 512;
    const int voff0 = lane * 8 + cg * 2 * 512;     // + kk*8192 + cf*512
    f32x4 oacc[4][2];
    #pragma unroll
    for (int qq = 0; qq < 4; ++qq) { oacc[qq][0] = fz; oacc[qq][1] = fz; }
    bf16x8 vA[2][2], vB[2][2];

    // ---- S-wave state (wid 8..15): skt = wid&3 (k-tile), h = (wid>>2)&1
    //      tiles (sqt=2h, skt) and (sqt=2h+1, skt); ONE K-frag per body.
    const int skt = wid & 3;
    const int h   = (wid >> 2) & 1;
    const int g0  = 4 * h + (skt >> 1);            // group of tile (2h, skt)
    const int g1  = g0 + 2;                        // group of tile (2h+1, skt)
    const int s8  = (skt & 1) * 2 + (quad >> 1);   // kb8 slot within group
    const int e4  = (quad & 1) * 4;                // element offset
    const _Float16* kbp = kg + (size_t)b * N_PIX * DQK;
    const int koff = (skt * 16 + L15) * DQK + quad * 8;
    f16x8 aq0{}, aq1{}, kA{}, kB{};
    float psum0 = 0.f, psum1 = 0.f;

    // ---- prologue
    if (is_pv) {
        #pragma unroll
        for (int kk = 0; kk < 2; ++kk)
            #pragma unroll
            for (int cf = 0; cf < 2; ++cf) {
                vA[kk][cf] = *(const bf16x8*)(vb +                 voff0 + kk * 8192 + cf * 512);
                vB[kk][cf] = *(const bf16x8*)(vb + (size_t)16384 + voff0 + kk * 8192 + cf * 512);
            }
    } else {
        aq0 = *(const f16x8*)(qg + ((size_t)b * N_PIX + n0 + (2 * h + 0) * 16 + L15) * DQK + quad * 8);
        aq1 = *(const f16x8*)(qg + ((size_t)b * N_PIX + n0 + (2 * h + 1) * 16 + L15) * DQK + quad * 8);
        const f16x8 k00 = *(const f16x8*)(kbp + koff);
        kA = *(const f16x8*)(kbp + (size_t)1 * 64 * DQK + koff);
        kB = *(const f16x8*)(kbp + (size_t)2 * 64 * DQK + koff);
        const f32x4 s0 = __builtin_amdgcn_mfma_f32_16x16x32_f16(k00, aq0, fz, 0, 0, 0);
        const f32x4 s1 = __builtin_amdgcn_mfma_f32_16x16x32_f16(k00, aq1, fz, 0, 0, 0);
        const float a0 = exp2f(s0[0]), a1 = exp2f(s0[1]);
        const float a2 = exp2f(s0[2]), a3 = exp2f(s0[3]);
        psum0 += (a0 + a1) + (a2 + a3);
        uint2 w0; w0.x = cvt_pk_bf16(a0, a1); w0.y = cvt_pk_bf16(a2, a3);
        *(uint2*)(&Ps[0][g0][s8][L15][e4]) = w0;
        const float b0 = exp2f(s1[0]), b1 = exp2f(s1[1]);
        const float b2 = exp2f(s1[2]), b3 = exp2f(s1[3]);
        psum1 += (b0 + b1) + (b2 + b3);
        uint2 w1; w1.x = cvt_pk_bf16(b0, b1); w1.y = cvt_pk_bf16(b2, b3);
        *(uint2*)(&Ps[0][g1][s8][L15][e4]) = w1;
    }
    barrier_lds();

    // ---- main loop: 64 bodies, x2 unrolled (P(J) lives in buf J&1)
    for (int it = 0; it < 64; it += 2) {
        if (is_pv) { PV_BODY(it, vA) } else { S_BODY(it, kA, true) }
        barrier_lds();
        if (is_pv) { PV_BODY(it + 1, vB) } else { S_BODY(it + 1, kB, it < 62) }
        barrier_lds();
    }

    // ---- epilogue: S waves publish row-sums, PV waves normalize + store
    if (!is_pv) {
        psum0 += __shfl_xor(psum0, 16, 64);
        psum0 += __shfl_xor(psum0, 32, 64);
        psum1 += __shfl_xor(psum1, 16, 64);
        psum1 += __shfl_xor(psum1, 32, 64);
        if (quad == 0) {
            lsum[2 * h + 0][skt][L15] = psum0;
            lsum[2 * h + 1][skt][L15] = psum1;
        }
    }
    __syncthreads();

    if (is_pv) {
        float* ob = out + (size_t)b * CCH * N_PIX;
        #pragma unroll
        for (int qq = 0; qq < 4; ++qq) {
            float inv_l[4];
            #pragma unroll
            for (int r = 0; r < 4; ++r) {
                const int q = quad * 4 + r;
                inv_l[r] = 1.f / (lsum[qq][0][q] + lsum[qq][1][q] +
                                  lsum[qq][2][q] + lsum[qq][3][q]);
            }
            #pragma unroll
            for (int cf = 0; cf < 2; ++cf) {
                const int c = cg * 32 + cf * 16 + L15;
                f32x4 o;
                #pragma unroll
                for (int r = 0; r < 4; ++r) o[r] = oacc[qq][cf][r] * inv_l[r];
                *(f32x4*)(ob + (size_t)c * N_PIX + n0 + qq * 16 + quad * 4) = o;
            }
        }
    }
}

// ---------------------------------------------------------------------------
extern "C" void kernel_launch(void* const* d_in, const int* in_sizes, int n_in,
                              void* d_out, int out_size, void* d_ws, size_t ws_size,
                              hipStream_t stream) {
    (void)in_sizes; (void)n_in; (void)out_size; (void)ws_size;
    const float* x  = (const float*)d_in[0];
    const float* Wq = (const float*)d_in[1];
    const float* bq = (const float*)d_in[2];
    const float* Wk = (const float*)d_in[3];
    const float* bk = (const float*)d_in[4];
    const float* Wv = (const float*)d_in[5];
    const float* bv = (const float*)d_in[6];

    // workspace: q 1MB | k 1MB | Vp 8MB | Wp 160KB
    _Float16* qb = (_Float16*)d_ws;
    _Float16* kb = qb + (size_t)4 * N_PIX * DQK;
    __hip_bfloat16* vpk = (__hip_bfloat16*)(kb + (size_t)4 * N_PIX * DQK);
    _Float16* wp = (_Float16*)(vpk + (size_t)4 * 2048 * 512);
    float* outp = (float*)d_out;

    wpack_kernel<<<40, 256, 0, stream>>>(Wq, Wk, Wv, wp);
    qkv_kernel<<<512, 640, 0, stream>>>(x, wp, bq, bk, bv, qb, kb, vpk);
    attn_kernel<<<256, 1024, 0, stream>>>(qb, kb, vpk, outp);
}